// Round 1
// baseline (231.400 us; speedup 1.0000x reference)
//
#include <hip/hip_runtime.h>

// Skeleton FK, algebraically simplified:
//   q[c] = q[parent] + R[b,parent] @ v[c],  v[c] = (off[c][1], off[c][2], off[c][0])
//   out[b,c,:] = q[c]
// Joints 10,11,15,22,23 are never parents -> their rotations are never loaded.

#define NJ 24

__global__ __launch_bounds__(256) void fk_kernel(
    const float* __restrict__ ori,   // [B, 24, 3, 3] row-major = [B, 216]
    const float* __restrict__ off,   // [24, 3]
    float* __restrict__ out,         // [B, 24, 3] = [B, 72]
    int B)
{
    int b = blockIdx.x * blockDim.x + threadIdx.x;
    if (b >= B) return;

    const float* __restrict__ row = ori + (size_t)b * 216;

    float qx[NJ], qy[NJ], qz[NJ];
    qx[0] = 0.0f; qy[0] = 0.0f; qz[0] = 0.0f;

    float r[9];

#define LOADR(p) { _Pragma("unroll") \
    for (int t = 0; t < 9; ++t) r[t] = row[9*(p) + t]; }

#define CHILD(p, c) { \
    const float vx = off[3*(c)+1]; \
    const float vy = off[3*(c)+2]; \
    const float vz = off[3*(c)+0]; \
    qx[c] = fmaf(r[0], vx, fmaf(r[1], vy, fmaf(r[2], vz, qx[p]))); \
    qy[c] = fmaf(r[3], vx, fmaf(r[4], vy, fmaf(r[5], vz, qy[p]))); \
    qz[c] = fmaf(r[6], vx, fmaf(r[7], vy, fmaf(r[8], vz, qz[p]))); }

    LOADR(0);  CHILD(0, 1);  CHILD(0, 2);  CHILD(0, 3);
    LOADR(1);  CHILD(1, 4);
    LOADR(2);  CHILD(2, 5);
    LOADR(3);  CHILD(3, 6);
    LOADR(4);  CHILD(4, 7);
    LOADR(5);  CHILD(5, 8);
    LOADR(6);  CHILD(6, 9);
    LOADR(7);  CHILD(7, 10);
    LOADR(8);  CHILD(8, 11);
    LOADR(9);  CHILD(9, 12); CHILD(9, 13); CHILD(9, 14);
    LOADR(12); CHILD(12, 15);
    LOADR(13); CHILD(13, 16);
    LOADR(14); CHILD(14, 17);
    LOADR(16); CHILD(16, 18);
    LOADR(17); CHILD(17, 19);
    LOADR(18); CHILD(18, 20);
    LOADR(19); CHILD(19, 21);
    LOADR(20); CHILD(20, 22);
    LOADR(21); CHILD(21, 23);

#undef LOADR
#undef CHILD

    // Pack and store as 18 aligned float4 (row base is 288B = 16-aligned).
    float f[72];
#pragma unroll
    for (int i = 0; i < NJ; ++i) {
        f[3*i + 0] = qx[i];
        f[3*i + 1] = qy[i];
        f[3*i + 2] = qz[i];
    }
    float4* __restrict__ o4 = (float4*)(out + (size_t)b * 72);
#pragma unroll
    for (int j = 0; j < 18; ++j) {
        o4[j] = make_float4(f[4*j + 0], f[4*j + 1], f[4*j + 2], f[4*j + 3]);
    }
}

extern "C" void kernel_launch(void* const* d_in, const int* in_sizes, int n_in,
                              void* d_out, int out_size, void* d_ws, size_t ws_size,
                              hipStream_t stream) {
    const float* ori = (const float*)d_in[0];   // [B,24,3,3] fp32
    const float* off = (const float*)d_in[1];   // [24,3] fp32
    float* out = (float*)d_out;                 // [B,24,3] fp32

    int B = in_sizes[0] / 216;   // 524288
    dim3 block(256);
    dim3 grid((B + 255) / 256);
    hipLaunchKernelGGL(fk_kernel, grid, block, 0, stream, ori, off, out, B);
}

// Round 2
// 154.958 us; speedup vs baseline: 1.4933x; 1.4933x over previous
//
#include <hip/hip_runtime.h>

// Skeleton FK, algebraically simplified (G cancels through the chain):
//   q[c] = q[parent] + R[b,parent] @ v[c],  v[c] = (off[c][1], off[c][2], off[c][0])
//   out[b,c,:] = q[c]
// Parents used: 0..9, 12..14, 16..21 (19 matrices = 171 floats of the 216/row).
// Strategy: hoist all 44 float4 input loads -> max MLP; FK in registers;
// stage output tile in LDS -> fully coalesced float4 stores.

#define NJ 24

__global__ __launch_bounds__(64, 2) void fk_kernel(
    const float* __restrict__ ori,   // [B, 24, 3, 3] = [B, 216]
    const float* __restrict__ off,   // [24, 3]
    float* __restrict__ out,         // [B, 24, 3] = [B, 72]
    int B)
{
    const int l = threadIdx.x;                       // 0..63, one wave per block
    const long long b = (long long)blockIdx.x * 64 + l;

    const float* __restrict__ row = ori + b * 216;

    // ---- Phase 1: hoist all needed loads (44 independent float4) ----
    // Segment A: joints 0..9   -> floats [0,90)   : 23 float4 covering [0,92)
    // Segment B: joints 12..14 -> floats [108,135): 7  float4 covering [108,136)
    // Segment C: joints 16..21 -> floats [144,198): 14 float4 covering [144,200)
    float Af[92], Bf[28], Cf[56];
    {
        const float4* __restrict__ a4 = (const float4*)(row);
        const float4* __restrict__ b4 = (const float4*)(row + 108);
        const float4* __restrict__ c4 = (const float4*)(row + 144);
#pragma unroll
        for (int i = 0; i < 23; ++i) {
            float4 t = a4[i];
            Af[4*i+0] = t.x; Af[4*i+1] = t.y; Af[4*i+2] = t.z; Af[4*i+3] = t.w;
        }
#pragma unroll
        for (int i = 0; i < 7; ++i) {
            float4 t = b4[i];
            Bf[4*i+0] = t.x; Bf[4*i+1] = t.y; Bf[4*i+2] = t.z; Bf[4*i+3] = t.w;
        }
#pragma unroll
        for (int i = 0; i < 14; ++i) {
            float4 t = c4[i];
            Cf[4*i+0] = t.x; Cf[4*i+1] = t.y; Cf[4*i+2] = t.z; Cf[4*i+3] = t.w;
        }
    }

    // ---- Phase 2: FK chain in registers (all indices compile-time) ----
    float qx[NJ], qy[NJ], qz[NJ];
    qx[0] = 0.0f; qy[0] = 0.0f; qz[0] = 0.0f;

#define CHILD(RF, b0, p, c) { \
    const float vx = off[3*(c)+1]; \
    const float vy = off[3*(c)+2]; \
    const float vz = off[3*(c)+0]; \
    qx[c] = fmaf(RF[(b0)+0], vx, fmaf(RF[(b0)+1], vy, fmaf(RF[(b0)+2], vz, qx[p]))); \
    qy[c] = fmaf(RF[(b0)+3], vx, fmaf(RF[(b0)+4], vy, fmaf(RF[(b0)+5], vz, qy[p]))); \
    qz[c] = fmaf(RF[(b0)+6], vx, fmaf(RF[(b0)+7], vy, fmaf(RF[(b0)+8], vz, qz[p]))); }

    CHILD(Af,  0, 0, 1);  CHILD(Af,  0, 0, 2);  CHILD(Af,  0, 0, 3);
    CHILD(Af,  9, 1, 4);
    CHILD(Af, 18, 2, 5);
    CHILD(Af, 27, 3, 6);
    CHILD(Af, 36, 4, 7);
    CHILD(Af, 45, 5, 8);
    CHILD(Af, 54, 6, 9);
    CHILD(Af, 63, 7, 10);
    CHILD(Af, 72, 8, 11);
    CHILD(Af, 81, 9, 12); CHILD(Af, 81, 9, 13); CHILD(Af, 81, 9, 14);
    CHILD(Bf,  0, 12, 15);
    CHILD(Bf,  9, 13, 16);
    CHILD(Bf, 18, 14, 17);
    CHILD(Cf,  0, 16, 18);
    CHILD(Cf,  9, 17, 19);
    CHILD(Cf, 18, 18, 20);
    CHILD(Cf, 27, 19, 21);
    CHILD(Cf, 36, 20, 22);
    CHILD(Cf, 45, 21, 23);
#undef CHILD

    // ---- Phase 3: stage output tile in LDS (64 rows x 288 B = 18 KiB) ----
    float fv[72];
#pragma unroll
    for (int i = 0; i < NJ; ++i) {
        fv[3*i+0] = qx[i];
        fv[3*i+1] = qy[i];
        fv[3*i+2] = qz[i];
    }

    __shared__ alignas(16) float so[64 * 72];
    float4* __restrict__ so4 = (float4*)so;
#pragma unroll
    for (int j = 0; j < 18; ++j)
        so4[l*18 + j] = make_float4(fv[4*j+0], fv[4*j+1], fv[4*j+2], fv[4*j+3]);

    __syncthreads();

    // ---- Phase 4: fully coalesced global stores (1 KiB/instruction) ----
    float4* __restrict__ o4 = (float4*)(out + (long long)blockIdx.x * 64 * 72);
#pragma unroll
    for (int i = 0; i < 18; ++i)
        o4[i*64 + l] = so4[i*64 + l];
}

extern "C" void kernel_launch(void* const* d_in, const int* in_sizes, int n_in,
                              void* d_out, int out_size, void* d_ws, size_t ws_size,
                              hipStream_t stream) {
    const float* ori = (const float*)d_in[0];   // [B,24,3,3] fp32
    const float* off = (const float*)d_in[1];   // [24,3] fp32
    float* out = (float*)d_out;                 // [B,24,3] fp32

    int B = in_sizes[0] / 216;                  // 524288
    dim3 block(64);
    dim3 grid(B / 64);                          // B is a multiple of 64
    hipLaunchKernelGGL(fk_kernel, grid, block, 0, stream, ori, off, out, B);
}

// Round 3
// 122.133 us; speedup vs baseline: 1.8947x; 1.2688x over previous
//
#include <hip/hip_runtime.h>

// Skeleton FK, algebraically simplified (frame-change G cancels):
//   q[c] = q[parent] + R[b,parent] @ v[c],  v[c] = (off[c][1], off[c][2], off[c][0])
//   out[b,c,:] = q[c]
//
// Round-3 structure: cooperative gather-compact global->LDS via
// global_load_lds (lane-contiguous LDS dest, near-contiguous global src),
// FK from LDS with conflict-free 45-f4 row stride, output staged in reused
// LDS (19-f4 padded stride) then fully coalesced float4 stores.
//
// Per global row (216 floats = 54 f4) the needed f4s are:
//   A: f4  0..22  (matrices 0..9)
//   B: f4 27..33  (matrices 12..14)
//   C: f4 36..49  (matrices 16..21)
// Compacted to 44 f4 + 1 pad = 45 f4 (720 B) per LDS row.

#define NJ 24

typedef const __attribute__((address_space(1))) void* gptr_t;
typedef __attribute__((address_space(3))) void* lptr_t;

__global__ __launch_bounds__(64, 2) void fk_kernel(
    const float* __restrict__ ori,   // [B, 216]
    const float* __restrict__ off,   // [24, 3]
    float* __restrict__ out,         // [B, 72]
    int B)
{
    const int l = threadIdx.x;                       // 0..63, one wave per block
    const long long tile = blockIdx.x;               // 64 rows per block
    const float* __restrict__ gbase = ori + tile * (64LL * 216);

    __shared__ alignas(16) float4 s4[64 * 45];       // 46080 B

    // ---- Phase 1: gather-compact global -> LDS (45 x 1KB DMA) ----
#pragma unroll
    for (int i = 0; i < 45; ++i) {
        const unsigned idx = (unsigned)(i * 64 + l);     // LDS f4 index
        const unsigned row = idx / 45u;                  // local row 0..63
        const unsigned w   = idx - row * 45u;            // compact f4 0..44
        const unsigned g   = (w < 23u) ? w
                           : (w < 30u) ? (w + 4u)
                           : (w < 44u) ? (w + 6u)
                           : 0u;                         // pad -> row f4 0
        const float* src = gbase + ((size_t)row * 54u + g) * 4u;
        __builtin_amdgcn_global_load_lds((gptr_t)src, (lptr_t)(&s4[i * 64]),
                                         16, 0, 0);
    }
    __syncthreads();   // vmcnt(0) + barrier

    // ---- Phase 2: FK chain from LDS (row base conflict-free, stride 45 f4) ----
    const float4* __restrict__ rbase = &s4[l * 45];

    float qx[NJ], qy[NJ], qz[NJ];
    qx[0] = 0.0f; qy[0] = 0.0f; qz[0] = 0.0f;

    float r[9];

    // Load matrix at compact float offset o (static): spans 3 f4s.
#define LOADM(o) { \
    const float4 w0 = rbase[(o)/4 + 0]; \
    const float4 w1 = rbase[(o)/4 + 1]; \
    const float4 w2 = rbase[(o)/4 + 2]; \
    const float tt[12] = {w0.x,w0.y,w0.z,w0.w, w1.x,w1.y,w1.z,w1.w, \
                          w2.x,w2.y,w2.z,w2.w}; \
    r[0]=tt[(o)%4+0]; r[1]=tt[(o)%4+1]; r[2]=tt[(o)%4+2]; \
    r[3]=tt[(o)%4+3]; r[4]=tt[(o)%4+4]; r[5]=tt[(o)%4+5]; \
    r[6]=tt[(o)%4+6]; r[7]=tt[(o)%4+7]; r[8]=tt[(o)%4+8]; }

#define CHILD(p, c) { \
    const float vx = off[3*(c)+1]; \
    const float vy = off[3*(c)+2]; \
    const float vz = off[3*(c)+0]; \
    qx[c] = fmaf(r[0], vx, fmaf(r[1], vy, fmaf(r[2], vz, qx[p]))); \
    qy[c] = fmaf(r[3], vx, fmaf(r[4], vy, fmaf(r[5], vz, qy[p]))); \
    qz[c] = fmaf(r[6], vx, fmaf(r[7], vy, fmaf(r[8], vz, qz[p]))); }

    // Compact float offsets: p0..9 -> 9p; p12..14 -> 9p-16; p16..21 -> 9p-24
    LOADM(0);   CHILD(0, 1);  CHILD(0, 2);  CHILD(0, 3);
    LOADM(9);   CHILD(1, 4);
    LOADM(18);  CHILD(2, 5);
    LOADM(27);  CHILD(3, 6);
    LOADM(36);  CHILD(4, 7);
    LOADM(45);  CHILD(5, 8);
    LOADM(54);  CHILD(6, 9);
    LOADM(63);  CHILD(7, 10);
    LOADM(72);  CHILD(8, 11);
    LOADM(81);  CHILD(9, 12); CHILD(9, 13); CHILD(9, 14);
    LOADM(92);  CHILD(12, 15);
    LOADM(101); CHILD(13, 16);
    LOADM(110); CHILD(14, 17);
    LOADM(120); CHILD(16, 18);
    LOADM(129); CHILD(17, 19);
    LOADM(138); CHILD(18, 20);
    LOADM(147); CHILD(19, 21);
    LOADM(156); CHILD(20, 22);
    LOADM(165); CHILD(21, 23);
#undef LOADM
#undef CHILD

    float fv[72];
#pragma unroll
    for (int i = 0; i < NJ; ++i) {
        fv[3*i+0] = qx[i];
        fv[3*i+1] = qy[i];
        fv[3*i+2] = qz[i];
    }

    // ---- Phase 3: stage output in reused LDS, stride 19 f4 (conflict-free) ----
    __syncthreads();   // all input reads done before overwrite

    float4* __restrict__ so4 = (float4*)s4;
#pragma unroll
    for (int j = 0; j < 18; ++j)
        so4[l * 19 + j] = make_float4(fv[4*j+0], fv[4*j+1], fv[4*j+2], fv[4*j+3]);

    __syncthreads();

    // ---- Phase 4: fully coalesced global stores (18 x 1KB) ----
    float4* __restrict__ o4 = (float4*)(out + tile * (64LL * 72));
#pragma unroll
    for (int j = 0; j < 18; ++j) {
        const unsigned g2   = (unsigned)(j * 64 + l);
        const unsigned row2 = g2 / 18u;
        const unsigned w2   = g2 - row2 * 18u;
        o4[g2] = so4[row2 * 19u + w2];
    }
}

extern "C" void kernel_launch(void* const* d_in, const int* in_sizes, int n_in,
                              void* d_out, int out_size, void* d_ws, size_t ws_size,
                              hipStream_t stream) {
    const float* ori = (const float*)d_in[0];   // [B,24,3,3] fp32
    const float* off = (const float*)d_in[1];   // [24,3] fp32
    float* out = (float*)d_out;                 // [B,24,3] fp32

    int B = in_sizes[0] / 216;                  // 524288
    dim3 block(64);
    dim3 grid(B / 64);                          // 8192 blocks, exact
    hipLaunchKernelGGL(fk_kernel, grid, block, 0, stream, ori, off, out, B);
}

// Round 4
// 119.708 us; speedup vs baseline: 1.9330x; 1.0203x over previous
//
#include <hip/hip_runtime.h>

// Skeleton FK, algebraically simplified (frame-change G cancels):
//   q[c] = q[parent] + R[b,parent] @ v[c],  v[c] = (off[c][1], off[c][2], off[c][0])
//   out[b,c,:] = q[c]
//
// Round-4: two-stage tree split to halve LDS (45KB -> 23KB) and double
// occupancy (3 -> 6 waves/CU).
//   Stage A: matrices 0..9   = row f4  0..22 (23 f4, stride 23) -> children 1..14
//   Stage B: matrices 12..14 = row f4 27..33, 16..21 = f4 36..49
//            compacted to 21 f4 (stride 21)                     -> children 15..23
// Output staged in the same buffer (stride 19) then coalesced stores.
// All strides odd -> uniform LDS bank load for ds_read_b128.

#define NJ 24

typedef const __attribute__((address_space(1))) void* gptr_t;
typedef __attribute__((address_space(3))) void* lptr_t;

__global__ __launch_bounds__(64) void fk_kernel(
    const float* __restrict__ ori,   // [B, 216]
    const float* __restrict__ off,   // [24, 3]
    float* __restrict__ out,         // [B, 72]
    int B)
{
    const int l = threadIdx.x;                       // 0..63, one wave per block
    const long long tile = blockIdx.x;               // 64 rows per block
    const float* __restrict__ gbase = ori + tile * (64LL * 216);

    __shared__ alignas(16) float4 s4[64 * 23];       // 23552 B

    float qx[NJ], qy[NJ], qz[NJ];
    qx[0] = 0.0f; qy[0] = 0.0f; qz[0] = 0.0f;

    // Matrix load from compact LDS row at float offset o (compile-time).
#define LOADM(RB, o) { \
    const float4 w0 = (RB)[(o)/4 + 0]; \
    const float4 w1 = (RB)[(o)/4 + 1]; \
    const float4 w2 = (RB)[(o)/4 + 2]; \
    const float tt[12] = {w0.x,w0.y,w0.z,w0.w, w1.x,w1.y,w1.z,w1.w, \
                          w2.x,w2.y,w2.z,w2.w}; \
    r[0]=tt[(o)%4+0]; r[1]=tt[(o)%4+1]; r[2]=tt[(o)%4+2]; \
    r[3]=tt[(o)%4+3]; r[4]=tt[(o)%4+4]; r[5]=tt[(o)%4+5]; \
    r[6]=tt[(o)%4+6]; r[7]=tt[(o)%4+7]; r[8]=tt[(o)%4+8]; }

#define CHILD(p, c) { \
    const float vx = off[3*(c)+1]; \
    const float vy = off[3*(c)+2]; \
    const float vz = off[3*(c)+0]; \
    qx[c] = fmaf(r[0], vx, fmaf(r[1], vy, fmaf(r[2], vz, qx[p]))); \
    qy[c] = fmaf(r[3], vx, fmaf(r[4], vy, fmaf(r[5], vz, qy[p]))); \
    qz[c] = fmaf(r[6], vx, fmaf(r[7], vy, fmaf(r[8], vz, qz[p]))); }

    // ---- Stage A gather: row f4 0..22, LDS stride 23 ----
#pragma unroll
    for (int i = 0; i < 23; ++i) {
        const unsigned idx = (unsigned)(i * 64 + l);
        const unsigned row = idx / 23u;
        const unsigned w   = idx - row * 23u;
        const float* src = gbase + (size_t)row * 216u + (size_t)w * 4u;
        __builtin_amdgcn_global_load_lds((gptr_t)src, (lptr_t)(&s4[i * 64]),
                                         16, 0, 0);
    }
    __syncthreads();   // vmcnt(0) + barrier: stage-A data resident

    // ---- Stage A compute: matrices 0..9 (compact float offset 9p) ----
    {
        const float4* __restrict__ rb = &s4[l * 23];
        float r[9];
        LOADM(rb, 0);   CHILD(0, 1);  CHILD(0, 2);  CHILD(0, 3);
        LOADM(rb, 9);   CHILD(1, 4);
        LOADM(rb, 18);  CHILD(2, 5);
        LOADM(rb, 27);  CHILD(3, 6);
        LOADM(rb, 36);  CHILD(4, 7);
        LOADM(rb, 45);  CHILD(5, 8);
        LOADM(rb, 54);  CHILD(6, 9);
        LOADM(rb, 63);  CHILD(7, 10);
        LOADM(rb, 72);  CHILD(8, 11);
        LOADM(rb, 81);  CHILD(9, 12); CHILD(9, 13); CHILD(9, 14);
    }
    __syncthreads();   // lgkmcnt(0): stage-A reads retired before DMA overwrite

    // ---- Stage B gather: row f4 27..33 & 36..49 -> compact 21 f4, stride 21 ----
#pragma unroll
    for (int i = 0; i < 21; ++i) {
        const unsigned idx = (unsigned)(i * 64 + l);
        const unsigned row = idx / 21u;
        const unsigned w   = idx - row * 21u;
        const unsigned g   = (w < 7u) ? (w + 27u) : (w + 29u);
        const float* src = gbase + (size_t)row * 216u + (size_t)g * 4u;
        __builtin_amdgcn_global_load_lds((gptr_t)src, (lptr_t)(&s4[i * 64]),
                                         16, 0, 0);
    }
    __syncthreads();   // vmcnt(0) + barrier: stage-B data resident

    // ---- Stage B compute ----
    // Compact float offsets: m12:0 m13:9 m14:18 m16:28 m17:37 m18:46
    //                        m19:55 m20:64 m21:73
    {
        const float4* __restrict__ rb = &s4[l * 21];
        float r[9];
        LOADM(rb, 0);   CHILD(12, 15);
        LOADM(rb, 9);   CHILD(13, 16);
        LOADM(rb, 18);  CHILD(14, 17);
        LOADM(rb, 28);  CHILD(16, 18);
        LOADM(rb, 37);  CHILD(17, 19);
        LOADM(rb, 46);  CHILD(18, 20);
        LOADM(rb, 55);  CHILD(19, 21);
        LOADM(rb, 64);  CHILD(20, 22);
        LOADM(rb, 73);  CHILD(21, 23);
    }
#undef LOADM
#undef CHILD

    float fv[72];
#pragma unroll
    for (int i = 0; i < NJ; ++i) {
        fv[3*i+0] = qx[i];
        fv[3*i+1] = qy[i];
        fv[3*i+2] = qz[i];
    }

    // ---- Stage output: same buffer, stride 19 f4 ----
    __syncthreads();   // stage-B reads retired before overwrite

    float4* __restrict__ so4 = (float4*)s4;
#pragma unroll
    for (int j = 0; j < 18; ++j)
        so4[l * 19 + j] = make_float4(fv[4*j+0], fv[4*j+1], fv[4*j+2], fv[4*j+3]);

    __syncthreads();

    // ---- Fully coalesced global stores (18 x 1KB) ----
    float4* __restrict__ o4 = (float4*)(out + tile * (64LL * 72));
#pragma unroll
    for (int j = 0; j < 18; ++j) {
        const unsigned g2   = (unsigned)(j * 64 + l);
        const unsigned row2 = g2 / 18u;
        const unsigned w2   = g2 - row2 * 18u;
        o4[g2] = so4[row2 * 19u + w2];
    }
}

extern "C" void kernel_launch(void* const* d_in, const int* in_sizes, int n_in,
                              void* d_out, int out_size, void* d_ws, size_t ws_size,
                              hipStream_t stream) {
    const float* ori = (const float*)d_in[0];   // [B,24,3,3] fp32
    const float* off = (const float*)d_in[1];   // [24,3] fp32
    float* out = (float*)d_out;                 // [B,24,3] fp32

    int B = in_sizes[0] / 216;                  // 524288
    dim3 block(64);
    dim3 grid(B / 64);                          // 8192 blocks, exact
    hipLaunchKernelGGL(fk_kernel, grid, block, 0, stream, ori, off, out, B);
}